// Round 7
// baseline (154.221 us; speedup 1.0000x reference)
//
#include <hip/hip_runtime.h>

typedef __attribute__((ext_vector_type(8))) short short8;
typedef __attribute__((ext_vector_type(4))) float f32x4;

__device__ __forceinline__ unsigned short f2bf(float f) {
    unsigned u = __builtin_bit_cast(unsigned, f);
    unsigned r = (u + 0x7FFFu + ((u >> 16) & 1u)) >> 16;
    return (unsigned short)r;
}
__device__ __forceinline__ float bf2f(unsigned short u) {
    unsigned v = ((unsigned)u) << 16;
    return __builtin_bit_cast(float, v);
}

__device__ __forceinline__ void gload16(const unsigned short* g, unsigned short* l) {
    __builtin_amdgcn_global_load_lds(
        (const __attribute__((address_space(1))) void*)g,
        (__attribute__((address_space(3))) void*)l,
        16, 0, 0);
}

#define WAITV(N) asm volatile("s_waitcnt vmcnt(" #N ")" ::: "memory")
#define BAR() do { asm volatile("" ::: "memory"); __builtin_amdgcn_s_barrier(); asm volatile("" ::: "memory"); } while (0)

// ---- hand-rolled grid barrier: ~1-3 us vs ~116 us for cg::grid.sync ----
// cnt at +0, gen at +128 (separate cachelines). Zeroed by hipMemsetAsync each call.
__device__ __forceinline__ void gbar(unsigned* cnt, unsigned* gen, unsigned nblk) {
    __syncthreads();
    if (threadIdx.x == 0) {
        __threadfence();                           // release: my writes visible device-wide
        unsigned g = atomicAdd(gen, 0u);           // read generation BEFORE arriving
        if (atomicAdd(cnt, 1u) == nblk - 1u) {     // last arriver
            atomicExch(cnt, 0u);                   // reset for next barrier
            __threadfence();
            atomicAdd(gen, 1u);                    // open next generation
        } else {
            while (atomicAdd(gen, 0u) == g) __builtin_amdgcn_s_sleep(2);
        }
        __threadfence();                           // acquire
    }
    __syncthreads();
}

// ---- fp32->bf16 one 8-elem chunk ----
__device__ __forceinline__ void cvt_chunk(const float* __restrict__ src,
                                          unsigned short* __restrict__ dst, int t) {
    const float4* s4 = (const float4*)src;
    float4 a = s4[2 * t], b = s4[2 * t + 1];
    union { unsigned short u[8]; int4 v; } r;
    r.u[0] = f2bf(a.x); r.u[1] = f2bf(a.y); r.u[2] = f2bf(a.z); r.u[3] = f2bf(a.w);
    r.u[4] = f2bf(b.x); r.u[5] = f2bf(b.y); r.u[6] = f2bf(b.z); r.u[7] = f2bf(b.w);
    ((int4*)dst)[t] = r.v;
}

// ---- batched per-expert NT GEMM stage, fused blend+bias epilogue (R4-validated) ----
__device__ __forceinline__ void gemm_stage(
    const unsigned short* __restrict__ A,
    const unsigned short* __restrict__ W,
    const float* __restrict__ blend, const float* __restrict__ bias,
    unsigned short* __restrict__ Y,
    int K, int N, int ldy, int nxt,
    unsigned short (&As)[3][128][32], unsigned short (&Bs)[3][128][32])
{
    const int bid = blockIdx.x;
    if (bid >= 64 * nxt) return;
    const int e   = bid / (8 * nxt);
    const int rem = bid - e * 8 * nxt;
    const int bm  = (rem / nxt) * 128;
    const int on  = (rem % nxt) * 128;

    const int t = threadIdx.x, lane = t & 63, w = t >> 6;
    const int wr = w >> 2, wc = w & 3;

    const unsigned short* Wt = W + (size_t)e * N * K;
    const int sr = lane >> 2, sc = (lane & 3) * 8;
    const int ra = w * 16 + sr;
    int rb = on + ra; if (rb > N - 1) rb = N - 1;
    const unsigned short* gA = A  + (size_t)(bm + ra) * K + sc;
    const unsigned short* gB = Wt + (size_t)rb * K + sc;

    const int ktn = K / 32;

#define STAGE(buf, kt) do { int _k0 = (kt) * 32;                       \
        gload16(gA + _k0, &As[(buf)][w * 16][0]);                      \
        gload16(gB + _k0, &Bs[(buf)][w * 16][0]); } while (0)

    f32x4 acc[4][2] = {};
    STAGE(0, 0); STAGE(1, 1); STAGE(2, 2);

    int cur = 0;
    for (int kt = 0; kt < ktn; ++kt) {
        int ahead = ktn - 1 - kt;
        if (ahead >= 2)      WAITV(4);
        else if (ahead == 1) WAITV(2);
        else                 WAITV(0);
        BAR();

        short8 af[4], bfr[2];
        #pragma unroll
        for (int fm = 0; fm < 4; ++fm)
            af[fm] = *(const short8*)&As[cur][wr * 64 + fm * 16 + (lane & 15)][(lane >> 4) * 8];
        #pragma unroll
        for (int fn = 0; fn < 2; ++fn)
            bfr[fn] = *(const short8*)&Bs[cur][wc * 32 + fn * 16 + (lane & 15)][(lane >> 4) * 8];
        #pragma unroll
        for (int fm = 0; fm < 4; ++fm)
            #pragma unroll
            for (int fn = 0; fn < 2; ++fn)
                acc[fm][fn] = __builtin_amdgcn_mfma_f32_16x16x32_bf16(
                    af[fm], bfr[fn], acc[fm][fn], 0, 0, 0);

        BAR();
        if (kt + 3 < ktn) STAGE(cur, kt + 3);
        cur = (cur == 2) ? 0 : cur + 1;
    }
#undef STAGE

    const float* blendE = blend + e * 1024;
    const float* biasE  = bias + (size_t)e * N;
    unsigned short* Ye  = Y + (size_t)e * 1024 * ldy;
    #pragma unroll
    for (int fm = 0; fm < 4; ++fm) {
        int i0 = bm + wr * 64 + fm * 16 + (lane >> 4) * 4;
        float4 bl = *(const float4*)&blendE[i0];
        #pragma unroll
        for (int fn = 0; fn < 2; ++fn) {
            int j = on + wc * 32 + fn * 16 + (lane & 15);
            if (j < N) {
                float bs = biasE[j];
                #pragma unroll
                for (int r = 0; r < 4; ++r)
                    Ye[(size_t)(i0 + r) * ldy + j] = f2bf((acc[fm][fn][r] + bs) * ((&bl.x)[r]));
            }
        }
    }
}

// ---- sum 8 bf16 planes + ELU -> bf16, all 131072 threads, 4 elems each ----
__device__ __forceinline__ void reduce8_stage(
    const unsigned short* __restrict__ Y, unsigned short* __restrict__ out)
{
    int idx = blockIdx.x * 512 + threadIdx.x;   // exactly 131072 = 1024*128
    int b  = idx >> 7;
    int o0 = (idx & 127) * 4;
    size_t base = (size_t)b * 512 + o0;
    float s[4] = {};
    #pragma unroll
    for (int p = 0; p < 8; ++p) {
        uint2 v = *(const uint2*)&Y[base + (size_t)p * 1024 * 512];
        const unsigned short* u = (const unsigned short*)&v;
        #pragma unroll
        for (int r = 0; r < 4; ++r) s[r] += bf2f(u[r]);
    }
    union { unsigned short u[4]; uint2 v; } rr;
    #pragma unroll
    for (int r = 0; r < 4; ++r) {
        float v = (s[r] > 0.f) ? s[r] : expm1f(s[r]);
        rr.u[r] = f2bf(v);
    }
    *(uint2*)&out[base] = rr.v;
}

// ---- final: sum 8 planes (ldy=320), fp32 out, N=311 ----
__device__ __forceinline__ void reduce_last_stage(
    const unsigned short* __restrict__ Y, float* __restrict__ out)
{
    int idx = blockIdx.x * 512 + threadIdx.x;
    if (idx >= 1024 * 40) return;
    int b  = idx / 40;
    int o0 = (idx - b * 40) * 8;
    size_t base = (size_t)b * 320 + o0;
    float s[8] = {};
    #pragma unroll
    for (int p = 0; p < 8; ++p) {
        int4 v = *(const int4*)&Y[base + (size_t)p * 1024 * 320];
        const unsigned short* u = (const unsigned short*)&v;
        #pragma unroll
        for (int r = 0; r < 8; ++r) s[r] += bf2f(u[r]);
    }
    #pragma unroll
    for (int r = 0; r < 8; ++r)
        if (o0 + r < 311) out[(size_t)b * 311 + o0 + r] = s[r];
}

// ================= cooperative mega-kernel, custom barrier =================
__global__ __launch_bounds__(512) void mega(
    const float* __restrict__ x,  const float* __restrict__ blend,
    const float* __restrict__ w0, const float* __restrict__ b0,
    const float* __restrict__ w1, const float* __restrict__ b1,
    const float* __restrict__ w2, const float* __restrict__ b2,
    float* __restrict__ out, char* __restrict__ ws)
{
    __shared__ unsigned short As[3][128][32];
    __shared__ unsigned short Bs[3][128][32];

    unsigned short* xb  = (unsigned short*)(ws + 0);
    unsigned short* w0b = (unsigned short*)(ws + 983040);
    unsigned short* w1b = (unsigned short*)(ws + 4915200);
    unsigned short* w2b = (unsigned short*)(ws + 9109504);
    unsigned short* h1b = (unsigned short*)(ws + 11657216);
    unsigned short* h2b = (unsigned short*)(ws + 12705792);
    unsigned short* yb  = (unsigned short*)(ws + 13754368);
    unsigned* bcnt = (unsigned*)(ws + 22142976);
    unsigned* bgen = (unsigned*)(ws + 22142976 + 128);

    const int bid = blockIdx.x;
    const int gid = bid * 512 + threadIdx.x;

#define GBAR() gbar(bcnt, bgen, 256u)

    // A: convert x (61440 chunks) + w0 (245760 chunks)
    for (int t = gid; t < 307200; t += 131072) {
        if (t < 61440) cvt_chunk(x, xb, t);
        else           cvt_chunk(w0, w0b, t - 61440);
    }
    GBAR();

    // B: G0 (K=480,N=512, 256 tiles) + tail-convert w1 (262144 chunks, 1024/block)
    gemm_stage(xb, w0b, blend, b0, yb, 480, 512, 512, 4, As, Bs);
    #pragma unroll
    for (int q = 0; q < 2; ++q)
        cvt_chunk(w1, w1b, bid * 1024 + q * 512 + threadIdx.x);
    GBAR();

    // C: R0
    reduce8_stage(yb, h1b);
    GBAR();

    // D: G1 (K=512,N=512) + tail-convert w2 (159232 chunks, 622/block)
    gemm_stage(h1b, w1b, blend, b1, yb, 512, 512, 512, 4, As, Bs);
    #pragma unroll
    for (int q = 0; q < 2; ++q) {
        int tl = q * 512 + threadIdx.x;
        if (tl < 622) cvt_chunk(w2, w2b, bid * 622 + tl);
    }
    GBAR();

    // E: R1
    reduce8_stage(yb, h2b);
    GBAR();

    // F: G2 (K=512,N=311,ldy=320, 192 tiles; blocks 192-255 idle)
    gemm_stage(h2b, w2b, blend, b2, yb, 512, 311, 320, 3, As, Bs);
    GBAR();

    // G: final reduce -> fp32 out
    reduce_last_stage(yb, out);
#undef GBAR
}

extern "C" void kernel_launch(void* const* d_in, const int* in_sizes, int n_in,
                              void* d_out, int out_size, void* d_ws, size_t ws_size,
                              hipStream_t stream) {
    const float* x     = (const float*)d_in[0];
    const float* blend = (const float*)d_in[1];
    const float* w0    = (const float*)d_in[2];
    const float* b0    = (const float*)d_in[3];
    const float* w1    = (const float*)d_in[4];
    const float* b1    = (const float*)d_in[5];
    const float* w2    = (const float*)d_in[6];
    const float* b2    = (const float*)d_in[7];
    float* out = (float*)d_out;
    char* ws   = (char*)d_ws;

    // zero barrier state (cnt, gen) — handles 0xAA poison; deterministic per call
    hipMemsetAsync(ws + 22142976, 0, 256, stream);

    void* args[] = {
        (void*)&x,  (void*)&blend, (void*)&w0, (void*)&b0,
        (void*)&w1, (void*)&b1,    (void*)&w2, (void*)&b2,
        (void*)&out, (void*)&ws
    };
    hipLaunchCooperativeKernel((const void*)mega, dim3(256), dim3(512),
                               args, 0, stream);
}

// Round 8
// 130.762 us; speedup vs baseline: 1.1794x; 1.1794x over previous
//
#include <hip/hip_runtime.h>

typedef __attribute__((ext_vector_type(8))) short short8;
typedef __attribute__((ext_vector_type(4))) float f32x4;

__device__ __forceinline__ unsigned short f2bf(float f) {
    unsigned u = __builtin_bit_cast(unsigned, f);
    unsigned r = (u + 0x7FFFu + ((u >> 16) & 1u)) >> 16;
    return (unsigned short)r;
}
__device__ __forceinline__ float bf2f(unsigned short u) {
    unsigned v = ((unsigned)u) << 16;
    return __builtin_bit_cast(float, v);
}

__device__ __forceinline__ void gload16(const unsigned short* g, unsigned short* l) {
    __builtin_amdgcn_global_load_lds(
        (const __attribute__((address_space(1))) void*)g,
        (__attribute__((address_space(3))) void*)l,
        16, 0, 0);
}

#define WAITV(N) asm volatile("s_waitcnt vmcnt(" #N ")" ::: "memory")
#define BAR() do { asm volatile("" ::: "memory"); __builtin_amdgcn_s_barrier(); asm volatile("" ::: "memory"); } while (0)

// ---- fused fp32 -> bf16 conversion: x, w0, w1, w2 (8 elems/thread) ----
// Also zeroes the 96 per-tile arrival counters (replay-safe re-init each call).
__global__ __launch_bounds__(256) void k_convert(
    const float* __restrict__ x,  const float* __restrict__ w0,
    const float* __restrict__ w1, const float* __restrict__ w2,
    unsigned short* __restrict__ xb,  unsigned short* __restrict__ w0b,
    unsigned short* __restrict__ w1b, unsigned short* __restrict__ w2b,
    unsigned* __restrict__ ctr)
{
    if (blockIdx.x == 0 && threadIdx.x < 96) ctr[threadIdx.x] = 0u;

    const int nx  = (1024 * 480) / 8;
    const int nw0 = (8 * 512 * 480) / 8;
    const int nw1 = (8 * 512 * 512) / 8;
    const int nw2 = (8 * 311 * 512) / 8;
    int t = blockIdx.x * 256 + threadIdx.x;
    const float* src; unsigned short* dst;
    if (t < nx)                { src = x;  dst = xb;  }
    else if ((t -= nx)  < nw0) { src = w0; dst = w0b; }
    else if ((t -= nw0) < nw1) { src = w1; dst = w1b; }
    else if ((t -= nw1) < nw2) { src = w2; dst = w2b; }
    else return;
    const float4* s4 = (const float4*)src;
    float4 a = s4[2 * t], b = s4[2 * t + 1];
    union { unsigned short u[8]; int4 v; } r;
    r.u[0] = f2bf(a.x); r.u[1] = f2bf(a.y); r.u[2] = f2bf(a.z); r.u[3] = f2bf(a.w);
    r.u[4] = f2bf(b.x); r.u[5] = f2bf(b.y); r.u[6] = f2bf(b.z); r.u[7] = f2bf(b.w);
    ((int4*)dst)[t] = r.v;
}

// ---- last-arriver tile reduction: sum 8 planes (+ELU->bf16 | ->fp32) ----
__device__ __forceinline__ void fused_reduce_tile(
    const unsigned short* __restrict__ Y, int bm, int on, int N, int ldy,
    void* __restrict__ hout, int elu_bf16)
{
    const size_t pstride = (size_t)1024 * ldy;
    if (elu_bf16) {
        // N=512: cols all valid, vectorized int4 (8 bf16)
        for (int q = threadIdx.x; q < 2048; q += 512) {   // 128 rows x 16 chunks
            int r = q >> 4, c8 = (q & 15) * 8;
            size_t base = (size_t)(bm + r) * ldy + on + c8;
            float s[8] = {};
            #pragma unroll
            for (int p = 0; p < 8; ++p) {
                int4 v = *(const int4*)&Y[base + (size_t)p * pstride];
                const unsigned short* u = (const unsigned short*)&v;
                #pragma unroll
                for (int k = 0; k < 8; ++k) s[k] += bf2f(u[k]);
            }
            union { unsigned short u[8]; int4 v; } rr;
            #pragma unroll
            for (int k = 0; k < 8; ++k) {
                float v = (s[k] > 0.f) ? s[k] : expm1f(s[k]);
                rr.u[k] = f2bf(v);
            }
            *(int4*)&((unsigned short*)hout)[(size_t)(bm + r) * 512 + on + c8] = rr.v;
        }
    } else {
        // final layer: fp32 out [1024][311], no activation
        int ncols = N - on; if (ncols > 128) ncols = 128;
        int total = 128 * ncols;
        for (int q = threadIdx.x; q < total; q += 512) {
            int r = q / ncols, j = on + q - r * ncols;
            size_t base = (size_t)(bm + r) * ldy + j;
            float s = 0.f;
            #pragma unroll
            for (int p = 0; p < 8; ++p) s += bf2f(Y[base + (size_t)p * pstride]);
            ((float*)hout)[(size_t)(bm + r) * N + j] = s;
        }
    }
}

// ---- per-expert NT GEMM + blend/bias plane write + last-block fused reduce ----
// grid.x = 8*8*nxt; e = bid&7 (matches XCD round-robin), rem = bid>>3 -> (bm,on)
__global__ __launch_bounds__(512) void k_gemm_fused(
    const unsigned short* __restrict__ A,
    const unsigned short* __restrict__ W,
    const float* __restrict__ blend,   // [E][1024]
    const float* __restrict__ bias,    // [E][N]
    unsigned short* __restrict__ Y,    // [8][1024][ldy] bf16 planes
    void* __restrict__ hout,           // bf16 [1024][512] or fp32 [1024][311]
    unsigned* __restrict__ ctr,        // [8*nxt] arrival counters (zeroed by cvt)
    int K, int N, int ldy, int nxt, int elu_bf16)
{
    __shared__ unsigned short As[3][128][32];  // 24 KB
    __shared__ unsigned short Bs[3][128][32];  // 24 KB
    __shared__ int s_isLast;

    const int bid = blockIdx.x;
    const int e   = bid & 7;
    const int rem = bid >> 3;
    const int bm  = (rem / nxt) * 128;
    const int on  = (rem % nxt) * 128;

    const int t = threadIdx.x, lane = t & 63, w = t >> 6;
    const int wr = w >> 2, wc = w & 3;

    const unsigned short* Wt = W + (size_t)e * N * K;
    const int sr = lane >> 2, sc = (lane & 3) * 8;
    const int ra = w * 16 + sr;
    int rb = on + ra; if (rb > N - 1) rb = N - 1;
    const unsigned short* gA = A  + (size_t)(bm + ra) * K + sc;
    const unsigned short* gB = Wt + (size_t)rb * K + sc;

    const int ktn = K / 32;

#define STAGE(buf, kt) do { int _k0 = (kt) * 32;                       \
        gload16(gA + _k0, &As[(buf)][w * 16][0]);                      \
        gload16(gB + _k0, &Bs[(buf)][w * 16][0]); } while (0)

    f32x4 acc[4][2] = {};
    STAGE(0, 0); STAGE(1, 1); STAGE(2, 2);

    int cur = 0;
    for (int kt = 0; kt < ktn; ++kt) {
        int ahead = ktn - 1 - kt;
        if (ahead >= 2)      WAITV(4);
        else if (ahead == 1) WAITV(2);
        else                 WAITV(0);
        BAR();

        short8 af[4], bfr[2];
        #pragma unroll
        for (int fm = 0; fm < 4; ++fm)
            af[fm] = *(const short8*)&As[cur][wr * 64 + fm * 16 + (lane & 15)][(lane >> 4) * 8];
        #pragma unroll
        for (int fn = 0; fn < 2; ++fn)
            bfr[fn] = *(const short8*)&Bs[cur][wc * 32 + fn * 16 + (lane & 15)][(lane >> 4) * 8];
        #pragma unroll
        for (int fm = 0; fm < 4; ++fm)
            #pragma unroll
            for (int fn = 0; fn < 2; ++fn)
                acc[fm][fn] = __builtin_amdgcn_mfma_f32_16x16x32_bf16(
                    af[fm], bfr[fn], acc[fm][fn], 0, 0, 0);

        BAR();
        if (kt + 3 < ktn) STAGE(cur, kt + 3);
        cur = (cur == 2) ? 0 : cur + 1;
    }
#undef STAGE

    // epilogue: plane e <- (acc + bias_e[j]) * blend_e[i], bf16
    const float* blendE = blend + e * 1024;
    const float* biasE  = bias + (size_t)e * N;
    unsigned short* Ye  = Y + (size_t)e * 1024 * ldy;
    #pragma unroll
    for (int fm = 0; fm < 4; ++fm) {
        int i0 = bm + wr * 64 + fm * 16 + (lane >> 4) * 4;
        float4 bl = *(const float4*)&blendE[i0];
        #pragma unroll
        for (int fn = 0; fn < 2; ++fn) {
            int j = on + wc * 32 + fn * 16 + (lane & 15);
            if (j < N) {
                float bs = biasE[j];
                #pragma unroll
                for (int r = 0; r < 4; ++r)
                    Ye[(size_t)(i0 + r) * ldy + j] = f2bf((acc[fm][fn][r] + bs) * ((&bl.x)[r]));
            }
        }
    }

    // signal arrival; 8th block for this (bm,on) tile performs the reduction
    __syncthreads();                       // drains vmcnt -> plane stores complete
    if (threadIdx.x == 0) {
        __threadfence();                   // L2 writeback: stores device-visible
        unsigned old = atomicAdd(&ctr[rem], 1u);
        s_isLast = (old == 7u);
    }
    __syncthreads();
    if (s_isLast) {
        __threadfence();                   // acquire
        fused_reduce_tile(Y, bm, on, N, ldy, hout, elu_bf16);
    }
}

extern "C" void kernel_launch(void* const* d_in, const int* in_sizes, int n_in,
                              void* d_out, int out_size, void* d_ws, size_t ws_size,
                              hipStream_t stream) {
    const float* x     = (const float*)d_in[0];
    const float* blend = (const float*)d_in[1];
    const float* w0    = (const float*)d_in[2];
    const float* b0    = (const float*)d_in[3];
    const float* w1    = (const float*)d_in[4];
    const float* b1    = (const float*)d_in[5];
    const float* w2    = (const float*)d_in[6];
    const float* b2    = (const float*)d_in[7];

    char* ws = (char*)d_ws;
    unsigned short* xb  = (unsigned short*)(ws + 0);          //   983,040
    unsigned short* w0b = (unsigned short*)(ws + 983040);     // 3,932,160
    unsigned short* w1b = (unsigned short*)(ws + 4915200);    // 4,194,304
    unsigned short* w2b = (unsigned short*)(ws + 9109504);    // 2,547,712
    unsigned short* h1b = (unsigned short*)(ws + 11657216);   // 1,048,576
    unsigned short* h2b = (unsigned short*)(ws + 12705792);   // 1,048,576
    unsigned short* yb  = (unsigned short*)(ws + 13754368);   // 8,388,608 (8 bf16 planes)
    unsigned* ctr       = (unsigned*)     (ws + 22142976);    // 96 counters (3 layers x 32)

    k_convert<<<2846, 256, 0, stream>>>(x, w0, w1, w2, xb, w0b, w1b, w2b, ctr);

    // layer 0: K=480, N=512, 256 blocks (8e x 8bm x 4on)
    k_gemm_fused<<<256, 512, 0, stream>>>(xb, w0b, blend, b0, yb, h1b, ctr,
                                          480, 512, 512, 4, 1);
    // layer 1: K=512, N=512
    k_gemm_fused<<<256, 512, 0, stream>>>(h1b, w1b, blend, b1, yb, h2b, ctr + 32,
                                          512, 512, 512, 4, 1);
    // layer 2: K=512, N=311 (ldy=320), fp32 out, 192 blocks (8e x 8bm x 3on)
    k_gemm_fused<<<192, 512, 0, stream>>>(h2b, w2b, blend, b2, yb, d_out, ctr + 64,
                                          512, 311, 320, 3, 0);
}

// Round 9
// 64.781 us; speedup vs baseline: 2.3806x; 2.0185x over previous
//
#include <hip/hip_runtime.h>

typedef __attribute__((ext_vector_type(8))) short short8;
typedef __attribute__((ext_vector_type(4))) float f32x4;

__device__ __forceinline__ unsigned short f2bf(float f) {
    unsigned u = __builtin_bit_cast(unsigned, f);
    unsigned r = (u + 0x7FFFu + ((u >> 16) & 1u)) >> 16;
    return (unsigned short)r;
}
__device__ __forceinline__ float bf2f(unsigned short u) {
    unsigned v = ((unsigned)u) << 16;
    return __builtin_bit_cast(float, v);
}

__device__ __forceinline__ void gload16(const unsigned short* g, unsigned short* l) {
    __builtin_amdgcn_global_load_lds(
        (const __attribute__((address_space(1))) void*)g,
        (__attribute__((address_space(3))) void*)l,
        16, 0, 0);
}

#define WAITV(N) asm volatile("s_waitcnt vmcnt(" #N ")" ::: "memory")
#define BAR() do { asm volatile("" ::: "memory"); __builtin_amdgcn_s_barrier(); asm volatile("" ::: "memory"); } while (0)

// ---- fp32->bf16 one 8-elem chunk ----
__device__ __forceinline__ void cvt_chunk(const float* __restrict__ src,
                                          unsigned short* __restrict__ dst, int t) {
    const float4* s4 = (const float4*)src;
    float4 a = s4[2 * t], b = s4[2 * t + 1];
    union { unsigned short u[8]; int4 v; } r;
    r.u[0] = f2bf(a.x); r.u[1] = f2bf(a.y); r.u[2] = f2bf(a.z); r.u[3] = f2bf(a.w);
    r.u[4] = f2bf(b.x); r.u[5] = f2bf(b.y); r.u[6] = f2bf(b.z); r.u[7] = f2bf(b.w);
    ((int4*)dst)[t] = r.v;
}

__device__ __forceinline__ short8 pack8(float4 a, float4 b) {
    short8 p;
    p[0] = (short)f2bf(a.x); p[1] = (short)f2bf(a.y);
    p[2] = (short)f2bf(a.z); p[3] = (short)f2bf(a.w);
    p[4] = (short)f2bf(b.x); p[5] = (short)f2bf(b.y);
    p[6] = (short)f2bf(b.z); p[7] = (short)f2bf(b.w);
    return p;
}

// ======== layer-0 GEMM: fp32 inputs staged directly (reg dbuf -> cvt -> LDS) ========
// x: [1024][480] fp32; w0: [8][512][480] fp32; Y: [8][1024][512] bf16 planes
// K=480 (15 K-tiles), N=512. Tail-converts w1 -> w1b (1024 chunks/block).
__global__ __launch_bounds__(512) void k_gemm0(
    const float* __restrict__ A, const float* __restrict__ W,
    const float* __restrict__ blend, const float* __restrict__ bias,
    unsigned short* __restrict__ Y,
    const float* __restrict__ csrc, unsigned short* __restrict__ cdst)
{
    __shared__ unsigned short As[2][128][32];  // 16 KB
    __shared__ unsigned short Bs[2][128][32];  // 16 KB

    const int e  = blockIdx.z;
    const int bm = blockIdx.y * 128;
    const int on = blockIdx.x * 128;
    const int t  = threadIdx.x, lane = t & 63, w = t >> 6;
    const int wr = w >> 2, wc = w & 3;

    const int sr = lane >> 2, sc = (lane & 3) * 8;
    const int ra = w * 16 + sr;
    const float* gA = A + (size_t)(bm + ra) * 480 + sc;
    const float* gB = W + ((size_t)e * 512 + (on + ra)) * 480 + sc;

    float4 a0, a1, b0v, b1v;
    a0  = *(const float4*)(gA + 0); a1  = *(const float4*)(gA + 4);
    b0v = *(const float4*)(gB + 0); b1v = *(const float4*)(gB + 4);

    f32x4 acc[4][2] = {};

    for (int kt = 0; kt < 15; ++kt) {
        const int buf = kt & 1;
        *(short8*)&As[buf][ra][sc] = pack8(a0, a1);
        *(short8*)&Bs[buf][ra][sc] = pack8(b0v, b1v);
        __syncthreads();                       // publish buf

        if (kt < 14) {                         // prefetch next tile (hidden under MFMA)
            int k0 = (kt + 1) * 32;
            a0  = *(const float4*)(gA + k0);     a1  = *(const float4*)(gA + k0 + 4);
            b0v = *(const float4*)(gB + k0);     b1v = *(const float4*)(gB + k0 + 4);
        }

        short8 af[4], bfr[2];
        #pragma unroll
        for (int fm = 0; fm < 4; ++fm)
            af[fm] = *(const short8*)&As[buf][wr * 64 + fm * 16 + (lane & 15)][(lane >> 4) * 8];
        #pragma unroll
        for (int fn = 0; fn < 2; ++fn)
            bfr[fn] = *(const short8*)&Bs[buf][wc * 32 + fn * 16 + (lane & 15)][(lane >> 4) * 8];
        #pragma unroll
        for (int fm = 0; fm < 4; ++fm)
            #pragma unroll
            for (int fn = 0; fn < 2; ++fn)
                acc[fm][fn] = __builtin_amdgcn_mfma_f32_16x16x32_bf16(
                    af[fm], bfr[fn], acc[fm][fn], 0, 0, 0);
        __syncthreads();                       // all reads of buf done
    }

    // epilogue: plane e <- (acc + bias_e[j]) * blend_e[i]
    const float* blendE = blend + e * 1024;
    const float* biasE  = bias + (size_t)e * 512;
    unsigned short* Ye  = Y + (size_t)e * 1024 * 512;
    #pragma unroll
    for (int fm = 0; fm < 4; ++fm) {
        int i0 = bm + wr * 64 + fm * 16 + (lane >> 4) * 4;
        float4 bl = *(const float4*)&blendE[i0];
        #pragma unroll
        for (int fn = 0; fn < 2; ++fn) {
            int j = on + wc * 32 + fn * 16 + (lane & 15);
            float bs = biasE[j];
            #pragma unroll
            for (int r = 0; r < 4; ++r)
                Ye[(size_t)(i0 + r) * 512 + j] = f2bf((acc[fm][fn][r] + bs) * ((&bl.x)[r]));
        }
    }

    // tail: convert w1 -> bf16 (1024 chunks per block, 256 blocks = 262144)
    int lb = (blockIdx.z * 8 + blockIdx.y) * 4 + blockIdx.x;
    cvt_chunk(csrc, cdst, lb * 1024 + threadIdx.x);
    cvt_chunk(csrc, cdst, lb * 1024 + 512 + threadIdx.x);
}

// ======== layers 1/2 GEMM: bf16, gload16 depth-3 pipeline (R4-validated) ========
__global__ __launch_bounds__(512) void k_gemm(
    const unsigned short* __restrict__ A,
    const unsigned short* __restrict__ W,
    const float* __restrict__ blend, const float* __restrict__ bias,
    unsigned short* __restrict__ Y,
    int K, int N, int ldy,
    const float* __restrict__ csrc, unsigned short* __restrict__ cdst, int nchunk)
{
    __shared__ unsigned short As[3][128][32];
    __shared__ unsigned short Bs[3][128][32];

    const int e  = blockIdx.z;
    const int bm = blockIdx.y * 128;
    const int on = blockIdx.x * 128;
    const int t  = threadIdx.x, lane = t & 63, w = t >> 6;
    const int wr = w >> 2, wc = w & 3;

    const unsigned short* Wt = W + (size_t)e * N * K;
    const int sr = lane >> 2, sc = (lane & 3) * 8;
    const int ra = w * 16 + sr;
    int rb = on + ra; if (rb > N - 1) rb = N - 1;
    const unsigned short* gA = A  + (size_t)(bm + ra) * K + sc;
    const unsigned short* gB = Wt + (size_t)rb * K + sc;

    const int ktn = K / 32;

#define STAGE(buf, kt) do { int _k0 = (kt) * 32;                       \
        gload16(gA + _k0, &As[(buf)][w * 16][0]);                      \
        gload16(gB + _k0, &Bs[(buf)][w * 16][0]); } while (0)

    f32x4 acc[4][2] = {};
    STAGE(0, 0); STAGE(1, 1); STAGE(2, 2);

    int cur = 0;
    for (int kt = 0; kt < ktn; ++kt) {
        int ahead = ktn - 1 - kt;
        if (ahead >= 2)      WAITV(4);
        else if (ahead == 1) WAITV(2);
        else                 WAITV(0);
        BAR();

        short8 af[4], bfr[2];
        #pragma unroll
        for (int fm = 0; fm < 4; ++fm)
            af[fm] = *(const short8*)&As[cur][wr * 64 + fm * 16 + (lane & 15)][(lane >> 4) * 8];
        #pragma unroll
        for (int fn = 0; fn < 2; ++fn)
            bfr[fn] = *(const short8*)&Bs[cur][wc * 32 + fn * 16 + (lane & 15)][(lane >> 4) * 8];
        #pragma unroll
        for (int fm = 0; fm < 4; ++fm)
            #pragma unroll
            for (int fn = 0; fn < 2; ++fn)
                acc[fm][fn] = __builtin_amdgcn_mfma_f32_16x16x32_bf16(
                    af[fm], bfr[fn], acc[fm][fn], 0, 0, 0);

        BAR();
        if (kt + 3 < ktn) STAGE(cur, kt + 3);
        cur = (cur == 2) ? 0 : cur + 1;
    }
#undef STAGE

    const float* blendE = blend + e * 1024;
    const float* biasE  = bias + (size_t)e * N;
    unsigned short* Ye  = Y + (size_t)e * 1024 * ldy;
    #pragma unroll
    for (int fm = 0; fm < 4; ++fm) {
        int i0 = bm + wr * 64 + fm * 16 + (lane >> 4) * 4;
        float4 bl = *(const float4*)&blendE[i0];
        #pragma unroll
        for (int fn = 0; fn < 2; ++fn) {
            int j = on + wc * 32 + fn * 16 + (lane & 15);
            if (j < N) {
                float bs = biasE[j];
                #pragma unroll
                for (int r = 0; r < 4; ++r)
                    Ye[(size_t)(i0 + r) * ldy + j] = f2bf((acc[fm][fn][r] + bs) * ((&bl.x)[r]));
            }
        }
    }

    // optional tail conversion (w2 during layer-1 GEMM)
    if (cdst) {
        int lb = (blockIdx.z * 8 + blockIdx.y) * gridDim.x + blockIdx.x;
        #pragma unroll
        for (int q = 0; q < 2; ++q) {
            int tl = q * 512 + threadIdx.x;
            if (tl < nchunk) cvt_chunk(csrc, cdst, lb * nchunk + tl);
        }
    }
}

// ---- sum 8 bf16 planes + ELU -> bf16 (N=512), 8 elems/thread ----
__global__ __launch_bounds__(256) void k_reduce8(
    const unsigned short* __restrict__ Y, unsigned short* __restrict__ out)
{
    int idx = blockIdx.x * 256 + threadIdx.x;
    int b  = idx >> 6;
    int o0 = (idx & 63) * 8;
    size_t base = (size_t)b * 512 + o0;
    float s[8] = {};
    #pragma unroll
    for (int p = 0; p < 8; ++p) {
        int4 v = *(const int4*)&Y[base + (size_t)p * 1024 * 512];
        const unsigned short* u = (const unsigned short*)&v;
        #pragma unroll
        for (int r = 0; r < 8; ++r) s[r] += bf2f(u[r]);
    }
    union { unsigned short u[8]; int4 v; } rr;
    #pragma unroll
    for (int r = 0; r < 8; ++r) {
        float v = (s[r] > 0.f) ? s[r] : expm1f(s[r]);
        rr.u[r] = f2bf(v);
    }
    *(int4*)&out[base] = rr.v;
}

// ---- final: sum 8 planes (ldy=320), fp32 out, N=311 ----
__global__ __launch_bounds__(256) void k_reduce_last(
    const unsigned short* __restrict__ Y, float* __restrict__ out)
{
    int idx = blockIdx.x * 256 + threadIdx.x;
    if (idx >= 1024 * 40) return;
    int b  = idx / 40;
    int o0 = (idx - b * 40) * 8;
    size_t base = (size_t)b * 320 + o0;
    float s[8] = {};
    #pragma unroll
    for (int p = 0; p < 8; ++p) {
        int4 v = *(const int4*)&Y[base + (size_t)p * 1024 * 320];
        const unsigned short* u = (const unsigned short*)&v;
        #pragma unroll
        for (int r = 0; r < 8; ++r) s[r] += bf2f(u[r]);
    }
    #pragma unroll
    for (int r = 0; r < 8; ++r)
        if (o0 + r < 311) out[(size_t)b * 311 + o0 + r] = s[r];
}

extern "C" void kernel_launch(void* const* d_in, const int* in_sizes, int n_in,
                              void* d_out, int out_size, void* d_ws, size_t ws_size,
                              hipStream_t stream) {
    const float* x     = (const float*)d_in[0];
    const float* blend = (const float*)d_in[1];
    const float* w0    = (const float*)d_in[2];
    const float* b0    = (const float*)d_in[3];
    const float* w1    = (const float*)d_in[4];
    const float* b1    = (const float*)d_in[5];
    const float* w2    = (const float*)d_in[6];
    const float* b2    = (const float*)d_in[7];

    char* ws = (char*)d_ws;
    unsigned short* w1b = (unsigned short*)(ws + 0);         // 4,194,304
    unsigned short* w2b = (unsigned short*)(ws + 4194304);   // 2,547,712
    unsigned short* h1b = (unsigned short*)(ws + 6742016);   // 1,048,576
    unsigned short* h2b = (unsigned short*)(ws + 7790592);   // 1,048,576
    unsigned short* yb  = (unsigned short*)(ws + 8839168);   // 8,388,608 (8 bf16 planes)
    // total ~17.2 MB

    // layer 0: fp32-direct GEMM + tail-convert w1
    k_gemm0<<<dim3(4, 8, 8), 512, 0, stream>>>(x, w0, blend, b0, yb, w1, w1b);
    k_reduce8<<<256, 256, 0, stream>>>(yb, h1b);

    // layer 1: bf16 GEMM + tail-convert w2 (622 chunks/block * 256 = 159232)
    k_gemm<<<dim3(4, 8, 8), 512, 0, stream>>>(h1b, w1b, blend, b1, yb, 512, 512, 512,
                                              w2, w2b, 622);
    k_reduce8<<<256, 256, 0, stream>>>(yb, h2b);

    // layer 2: bf16 GEMM, N=311 (ldy=320)
    k_gemm<<<dim3(3, 8, 8), 512, 0, stream>>>(h2b, w2b, blend, b2, yb, 512, 311, 320,
                                              nullptr, nullptr, 0);
    k_reduce_last<<<160, 256, 0, stream>>>(yb, (float*)d_out);
}

// Round 10
// 62.486 us; speedup vs baseline: 2.4681x; 1.0367x over previous
//
#include <hip/hip_runtime.h>

typedef __attribute__((ext_vector_type(8))) short short8;
typedef __attribute__((ext_vector_type(4))) float f32x4;

__device__ __forceinline__ unsigned short f2bf(float f) {
    unsigned u = __builtin_bit_cast(unsigned, f);
    unsigned r = (u + 0x7FFFu + ((u >> 16) & 1u)) >> 16;
    return (unsigned short)r;
}
__device__ __forceinline__ float bf2f(unsigned short u) {
    unsigned v = ((unsigned)u) << 16;
    return __builtin_bit_cast(float, v);
}

__device__ __forceinline__ void gload16(const unsigned short* g, unsigned short* l) {
    __builtin_amdgcn_global_load_lds(
        (const __attribute__((address_space(1))) void*)g,
        (__attribute__((address_space(3))) void*)l,
        16, 0, 0);
}

#define WAITV(N) asm volatile("s_waitcnt vmcnt(" #N ")" ::: "memory")
#define BAR() do { asm volatile("" ::: "memory"); __builtin_amdgcn_s_barrier(); asm volatile("" ::: "memory"); } while (0)

// ---- LDS tile swizzle: [128][32] bf16 tile (64B rows). 8-way -> <=2-way. ----
// byte off ^= ((off>>7)&7)<<4  == granule g ^= (g>>3)&7 ; involutive, stays in tile.
__device__ __forceinline__ short8 lds_read_swz(const unsigned short* tile, int row, int colb) {
    int off = row * 64 + colb;
    off ^= ((off >> 7) & 7) << 4;
    return *(const short8*)((const char*)tile + off);
}

// ---- fp32->bf16 one 8-elem chunk ----
__device__ __forceinline__ void cvt_chunk(const float* __restrict__ src,
                                          unsigned short* __restrict__ dst, int t) {
    const float4* s4 = (const float4*)src;
    float4 a = s4[2 * t], b = s4[2 * t + 1];
    union { unsigned short u[8]; int4 v; } r;
    r.u[0] = f2bf(a.x); r.u[1] = f2bf(a.y); r.u[2] = f2bf(a.z); r.u[3] = f2bf(a.w);
    r.u[4] = f2bf(b.x); r.u[5] = f2bf(b.y); r.u[6] = f2bf(b.z); r.u[7] = f2bf(b.w);
    ((int4*)dst)[t] = r.v;
}

__device__ __forceinline__ short8 pack8(float4 a, float4 b) {
    short8 p;
    p[0] = (short)f2bf(a.x); p[1] = (short)f2bf(a.y);
    p[2] = (short)f2bf(a.z); p[3] = (short)f2bf(a.w);
    p[4] = (short)f2bf(b.x); p[5] = (short)f2bf(b.y);
    p[6] = (short)f2bf(b.z); p[7] = (short)f2bf(b.w);
    return p;
}

// ======== layer-0 GEMM: fp32 staged via reg dbuf -> cvt -> swizzled ds_write ========
__global__ __launch_bounds__(512) void k_gemm0(
    const float* __restrict__ A, const float* __restrict__ W,
    const float* __restrict__ blend, const float* __restrict__ bias,
    unsigned short* __restrict__ Y,
    const float* __restrict__ csrc, unsigned short* __restrict__ cdst)
{
    __shared__ unsigned short As[2][4096];  // [128][32] bf16, swizzled
    __shared__ unsigned short Bs[2][4096];

    const int e  = blockIdx.z;
    const int bm = blockIdx.y * 128;
    const int on = blockIdx.x * 128;
    const int t  = threadIdx.x, lane = t & 63, w = t >> 6;
    const int wr = w >> 2, wc = w & 3;

    const int sr = lane >> 2, sce = (lane & 3) * 8;    // natural lane coords
    const int ra = w * 16 + sr;
    const float* gA = A + (size_t)(bm + ra) * 480 + sce;
    const float* gB = W + ((size_t)e * 512 + (on + ra)) * 480 + sce;

    int woff = ra * 64 + (lane & 3) * 16;              // logical byte offset
    woff ^= ((woff >> 7) & 7) << 4;                    // swizzled write slot

    float4 a0, a1, b0v, b1v;
    a0  = *(const float4*)(gA + 0); a1  = *(const float4*)(gA + 4);
    b0v = *(const float4*)(gB + 0); b1v = *(const float4*)(gB + 4);

    f32x4 acc[4][2] = {};

    for (int kt = 0; kt < 15; ++kt) {
        const int buf = kt & 1;
        *(short8*)((char*)As[buf] + woff) = pack8(a0, a1);
        *(short8*)((char*)Bs[buf] + woff) = pack8(b0v, b1v);
        __syncthreads();                       // publish buf

        if (kt < 14) {                         // prefetch next tile under MFMA
            int k0 = (kt + 1) * 32;
            a0  = *(const float4*)(gA + k0);     a1  = *(const float4*)(gA + k0 + 4);
            b0v = *(const float4*)(gB + k0);     b1v = *(const float4*)(gB + k0 + 4);
        }

        short8 af[4], bfr[2];
        #pragma unroll
        for (int fm = 0; fm < 4; ++fm)
            af[fm] = lds_read_swz(As[buf], wr * 64 + fm * 16 + (lane & 15), (lane >> 4) * 16);
        #pragma unroll
        for (int fn = 0; fn < 2; ++fn)
            bfr[fn] = lds_read_swz(Bs[buf], wc * 32 + fn * 16 + (lane & 15), (lane >> 4) * 16);
        #pragma unroll
        for (int fm = 0; fm < 4; ++fm)
            #pragma unroll
            for (int fn = 0; fn < 2; ++fn)
                acc[fm][fn] = __builtin_amdgcn_mfma_f32_16x16x32_bf16(
                    af[fm], bfr[fn], acc[fm][fn], 0, 0, 0);
        __syncthreads();
    }

    const float* blendE = blend + e * 1024;
    const float* biasE  = bias + (size_t)e * 512;
    unsigned short* Ye  = Y + (size_t)e * 1024 * 512;
    #pragma unroll
    for (int fm = 0; fm < 4; ++fm) {
        int i0 = bm + wr * 64 + fm * 16 + (lane >> 4) * 4;
        float4 bl = *(const float4*)&blendE[i0];
        #pragma unroll
        for (int fn = 0; fn < 2; ++fn) {
            int j = on + wc * 32 + fn * 16 + (lane & 15);
            float bs = biasE[j];
            #pragma unroll
            for (int r = 0; r < 4; ++r)
                Ye[(size_t)(i0 + r) * 512 + j] = f2bf((acc[fm][fn][r] + bs) * ((&bl.x)[r]));
        }
    }

    // tail: convert w1 -> bf16 (1024 chunks per block)
    int lb = (blockIdx.z * 8 + blockIdx.y) * 4 + blockIdx.x;
    cvt_chunk(csrc, cdst, lb * 1024 + threadIdx.x);
    cvt_chunk(csrc, cdst, lb * 1024 + 512 + threadIdx.x);
}

// ======== layers 1/2: bf16 gload16 depth-3 pipeline, pre-swizzled source ========
__global__ __launch_bounds__(512) void k_gemm(
    const unsigned short* __restrict__ A,
    const unsigned short* __restrict__ W,
    const float* __restrict__ blend, const float* __restrict__ bias,
    unsigned short* __restrict__ Y,
    int K, int N, int ldy,
    const float* __restrict__ csrc, unsigned short* __restrict__ cdst, int nchunk)
{
    __shared__ unsigned short As[3][4096];
    __shared__ unsigned short Bs[3][4096];

    const int e  = blockIdx.z;
    const int bm = blockIdx.y * 128;
    const int on = blockIdx.x * 128;
    const int t  = threadIdx.x, lane = t & 63, w = t >> 6;
    const int wr = w >> 2, wc = w & 3;

    const unsigned short* Wt = W + (size_t)e * N * K;
    // pre-swizzled source: lane l fetches global chunk of lane l2 = l ^ ((l>>3)&7),
    // so the forced-linear gload16 dest leaves the tile XOR-swizzled in LDS (rule #21).
    const int l2 = lane ^ ((lane >> 3) & 7);
    const int sr = l2 >> 2, sce = (l2 & 3) * 8;
    const int ra = w * 16 + sr;
    int rb = on + ra; if (rb > N - 1) rb = N - 1;
    const unsigned short* gA = A  + (size_t)(bm + ra) * K + sce;
    const unsigned short* gB = Wt + (size_t)rb * K + sce;

    const int ktn = K / 32;

#define STAGE(buf, kt) do { int _k0 = (kt) * 32;                       \
        gload16(gA + _k0, &As[(buf)][w * 512]);                        \
        gload16(gB + _k0, &Bs[(buf)][w * 512]); } while (0)

    f32x4 acc[4][2] = {};
    STAGE(0, 0); STAGE(1, 1); STAGE(2, 2);

    int cur = 0;
    for (int kt = 0; kt < ktn; ++kt) {
        int ahead = ktn - 1 - kt;
        if (ahead >= 2)      WAITV(4);
        else if (ahead == 1) WAITV(2);
        else                 WAITV(0);
        BAR();

        short8 af[4], bfr[2];
        #pragma unroll
        for (int fm = 0; fm < 4; ++fm)
            af[fm] = lds_read_swz(As[cur], wr * 64 + fm * 16 + (lane & 15), (lane >> 4) * 16);
        #pragma unroll
        for (int fn = 0; fn < 2; ++fn)
            bfr[fn] = lds_read_swz(Bs[cur], wc * 32 + fn * 16 + (lane & 15), (lane >> 4) * 16);
        #pragma unroll
        for (int fm = 0; fm < 4; ++fm)
            #pragma unroll
            for (int fn = 0; fn < 2; ++fn)
                acc[fm][fn] = __builtin_amdgcn_mfma_f32_16x16x32_bf16(
                    af[fm], bfr[fn], acc[fm][fn], 0, 0, 0);

        BAR();
        if (kt + 3 < ktn) STAGE(cur, kt + 3);
        cur = (cur == 2) ? 0 : cur + 1;
    }
#undef STAGE

    const float* blendE = blend + e * 1024;
    const float* biasE  = bias + (size_t)e * N;
    unsigned short* Ye  = Y + (size_t)e * 1024 * ldy;
    #pragma unroll
    for (int fm = 0; fm < 4; ++fm) {
        int i0 = bm + wr * 64 + fm * 16 + (lane >> 4) * 4;
        float4 bl = *(const float4*)&blendE[i0];
        #pragma unroll
        for (int fn = 0; fn < 2; ++fn) {
            int j = on + wc * 32 + fn * 16 + (lane & 15);
            if (j < N) {
                float bs = biasE[j];
                #pragma unroll
                for (int r = 0; r < 4; ++r)
                    Ye[(size_t)(i0 + r) * ldy + j] = f2bf((acc[fm][fn][r] + bs) * ((&bl.x)[r]));
            }
        }
    }

    if (cdst) {
        int lb = (blockIdx.z * 8 + blockIdx.y) * gridDim.x + blockIdx.x;
        #pragma unroll
        for (int q = 0; q < 2; ++q) {
            int tl = q * 512 + threadIdx.x;
            if (tl < nchunk) cvt_chunk(csrc, cdst, lb * nchunk + tl);
        }
    }
}

// ---- sum 8 bf16 planes + ELU -> bf16 (N=512), 8 elems/thread ----
__global__ __launch_bounds__(256) void k_reduce8(
    const unsigned short* __restrict__ Y, unsigned short* __restrict__ out)
{
    int idx = blockIdx.x * 256 + threadIdx.x;
    int b  = idx >> 6;
    int o0 = (idx & 63) * 8;
    size_t base = (size_t)b * 512 + o0;
    float s[8] = {};
    #pragma unroll
    for (int p = 0; p < 8; ++p) {
        int4 v = *(const int4*)&Y[base + (size_t)p * 1024 * 512];
        const unsigned short* u = (const unsigned short*)&v;
        #pragma unroll
        for (int r = 0; r < 8; ++r) s[r] += bf2f(u[r]);
    }
    union { unsigned short u[8]; int4 v; } rr;
    #pragma unroll
    for (int r = 0; r < 8; ++r) {
        float v = (s[r] > 0.f) ? s[r] : expm1f(s[r]);
        rr.u[r] = f2bf(v);
    }
    *(int4*)&out[base] = rr.v;
}

// ---- final: sum 8 planes (ldy=320), fp32 out, N=311 ----
__global__ __launch_bounds__(256) void k_reduce_last(
    const unsigned short* __restrict__ Y, float* __restrict__ out)
{
    int idx = blockIdx.x * 256 + threadIdx.x;
    if (idx >= 1024 * 40) return;
    int b  = idx / 40;
    int o0 = (idx - b * 40) * 8;
    size_t base = (size_t)b * 320 + o0;
    float s[8] = {};
    #pragma unroll
    for (int p = 0; p < 8; ++p) {
        int4 v = *(const int4*)&Y[base + (size_t)p * 1024 * 320];
        const unsigned short* u = (const unsigned short*)&v;
        #pragma unroll
        for (int r = 0; r < 8; ++r) s[r] += bf2f(u[r]);
    }
    #pragma unroll
    for (int r = 0; r < 8; ++r)
        if (o0 + r < 311) out[(size_t)b * 311 + o0 + r] = s[r];
}

extern "C" void kernel_launch(void* const* d_in, const int* in_sizes, int n_in,
                              void* d_out, int out_size, void* d_ws, size_t ws_size,
                              hipStream_t stream) {
    const float* x     = (const float*)d_in[0];
    const float* blend = (const float*)d_in[1];
    const float* w0    = (const float*)d_in[2];
    const float* b0    = (const float*)d_in[3];
    const float* w1    = (const float*)d_in[4];
    const float* b1    = (const float*)d_in[5];
    const float* w2    = (const float*)d_in[6];
    const float* b2    = (const float*)d_in[7];

    char* ws = (char*)d_ws;
    unsigned short* w1b = (unsigned short*)(ws + 0);         // 4,194,304
    unsigned short* w2b = (unsigned short*)(ws + 4194304);   // 2,547,712
    unsigned short* h1b = (unsigned short*)(ws + 6742016);   // 1,048,576
    unsigned short* h2b = (unsigned short*)(ws + 7790592);   // 1,048,576
    unsigned short* yb  = (unsigned short*)(ws + 8839168);   // 8,388,608 (8 bf16 planes)

    // layer 0: fp32-direct GEMM + tail-convert w1
    k_gemm0<<<dim3(4, 8, 8), 512, 0, stream>>>(x, w0, blend, b0, yb, w1, w1b);
    k_reduce8<<<256, 256, 0, stream>>>(yb, h1b);

    // layer 1: bf16 GEMM + tail-convert w2
    k_gemm<<<dim3(4, 8, 8), 512, 0, stream>>>(h1b, w1b, blend, b1, yb, 512, 512, 512,
                                              w2, w2b, 622);
    k_reduce8<<<256, 256, 0, stream>>>(yb, h2b);

    // layer 2: bf16 GEMM, N=311 (ldy=320)
    k_gemm<<<dim3(3, 8, 8), 512, 0, stream>>>(h2b, w2b, blend, b2, yb, 512, 311, 320,
                                              nullptr, nullptr, 0);
    k_reduce_last<<<160, 256, 0, stream>>>(yb, (float*)d_out);
}

// Round 11
// 54.132 us; speedup vs baseline: 2.8490x; 1.1543x over previous
//
#include <hip/hip_runtime.h>

typedef __attribute__((ext_vector_type(8))) short short8;
typedef __attribute__((ext_vector_type(4))) float f32x4;

__device__ __forceinline__ unsigned short f2bf(float f) {
    unsigned u = __builtin_bit_cast(unsigned, f);
    unsigned r = (u + 0x7FFFu + ((u >> 16) & 1u)) >> 16;
    return (unsigned short)r;
}
__device__ __forceinline__ float bf2f(unsigned short u) {
    unsigned v = ((unsigned)u) << 16;
    return __builtin_bit_cast(float, v);
}

__device__ __forceinline__ void gload16(const unsigned short* g, unsigned short* l) {
    __builtin_amdgcn_global_load_lds(
        (const __attribute__((address_space(1))) void*)g,
        (__attribute__((address_space(3))) void*)l,
        16, 0, 0);
}

#define WAITV(N) asm volatile("s_waitcnt vmcnt(" #N ")" ::: "memory")
#define WAITL0() asm volatile("s_waitcnt lgkmcnt(0)" ::: "memory")
#define BAR() do { asm volatile("" ::: "memory"); __builtin_amdgcn_s_barrier(); asm volatile("" ::: "memory"); } while (0)

// ---- LDS tile swizzle: [128][32] bf16 tile (64B rows). 8-way -> <=2-way. ----
__device__ __forceinline__ short8 lds_read_swz(const unsigned short* tile, int row, int colb) {
    int off = row * 64 + colb;
    off ^= ((off >> 7) & 7) << 4;
    return *(const short8*)((const char*)tile + off);
}

// ---- fp32->bf16 one 8-elem chunk ----
__device__ __forceinline__ void cvt_chunk(const float* __restrict__ src,
                                          unsigned short* __restrict__ dst, int t) {
    const float4* s4 = (const float4*)src;
    float4 a = s4[2 * t], b = s4[2 * t + 1];
    union { unsigned short u[8]; int4 v; } r;
    r.u[0] = f2bf(a.x); r.u[1] = f2bf(a.y); r.u[2] = f2bf(a.z); r.u[3] = f2bf(a.w);
    r.u[4] = f2bf(b.x); r.u[5] = f2bf(b.y); r.u[6] = f2bf(b.z); r.u[7] = f2bf(b.w);
    ((int4*)dst)[t] = r.v;
}

__device__ __forceinline__ short8 pack8(float4 a, float4 b) {
    short8 p;
    p[0] = (short)f2bf(a.x); p[1] = (short)f2bf(a.y);
    p[2] = (short)f2bf(a.z); p[3] = (short)f2bf(a.w);
    p[4] = (short)f2bf(b.x); p[5] = (short)f2bf(b.y);
    p[6] = (short)f2bf(b.z); p[7] = (short)f2bf(b.w);
    return p;
}

// ======== layer-0 GEMM: fp32 reg-staged depth-3, LDS dbuf, 1 barrier/iter ========
// x: [1024][480] fp32; w0: [8][512][480] fp32. K=480 (15 tiles), N=512.
__global__ __launch_bounds__(512) void k_gemm0(
    const float* __restrict__ A, const float* __restrict__ W,
    const float* __restrict__ blend, const float* __restrict__ bias,
    unsigned short* __restrict__ Y,
    const float* __restrict__ csrc, unsigned short* __restrict__ cdst)
{
    __shared__ unsigned short As[2][4096];  // [128][32] bf16, swizzled
    __shared__ unsigned short Bs[2][4096];

    const int e  = blockIdx.z;
    const int bm = blockIdx.y * 128;
    const int on = blockIdx.x * 128;
    const int t  = threadIdx.x, lane = t & 63, w = t >> 6;
    const int wr = w >> 2, wc = w & 3;

    const int sr = lane >> 2, sce = (lane & 3) * 8;
    const int ra = w * 16 + sr;
    const float* gA = A + (size_t)(bm + ra) * 480 + sce;
    const float* gB = W + ((size_t)e * 512 + (on + ra)) * 480 + sce;

    int woff = ra * 64 + (lane & 3) * 16;
    woff ^= ((woff >> 7) & 7) << 4;

    float4 La0[3], La1[3], Lb0[3], Lb1[3];
    #pragma unroll
    for (int s = 0; s < 3; ++s) {
        int k0 = s * 32;
        La0[s] = *(const float4*)(gA + k0); La1[s] = *(const float4*)(gA + k0 + 4);
        Lb0[s] = *(const float4*)(gB + k0); Lb1[s] = *(const float4*)(gB + k0 + 4);
    }

    f32x4 acc[4][2] = {};

    #pragma unroll
    for (int kt = 0; kt < 15; ++kt) {
        const int s = kt % 3, buf = kt & 1;
        *(short8*)((char*)As[buf] + woff) = pack8(La0[s], La1[s]);
        *(short8*)((char*)Bs[buf] + woff) = pack8(Lb0[s], Lb1[s]);
        WAITL0();                            // ds_write visible
        BAR();                               // publish buf (single barrier/iter)
        if (kt + 3 < 15) {                   // refill set s (3 tiles ahead)
            int k0 = (kt + 3) * 32;
            La0[s] = *(const float4*)(gA + k0); La1[s] = *(const float4*)(gA + k0 + 4);
            Lb0[s] = *(const float4*)(gB + k0); Lb1[s] = *(const float4*)(gB + k0 + 4);
        }
        short8 af[4], bfr[2];
        #pragma unroll
        for (int fm = 0; fm < 4; ++fm)
            af[fm] = lds_read_swz(As[buf], wr * 64 + fm * 16 + (lane & 15), (lane >> 4) * 16);
        #pragma unroll
        for (int fn = 0; fn < 2; ++fn)
            bfr[fn] = lds_read_swz(Bs[buf], wc * 32 + fn * 16 + (lane & 15), (lane >> 4) * 16);
        #pragma unroll
        for (int fm = 0; fm < 4; ++fm)
            #pragma unroll
            for (int fn = 0; fn < 2; ++fn)
                acc[fm][fn] = __builtin_amdgcn_mfma_f32_16x16x32_bf16(
                    af[fm], bfr[fn], acc[fm][fn], 0, 0, 0);
    }

    const float* blendE = blend + e * 1024;
    const float* biasE  = bias + (size_t)e * 512;
    unsigned short* Ye  = Y + (size_t)e * 1024 * 512;
    #pragma unroll
    for (int fm = 0; fm < 4; ++fm) {
        int i0 = bm + wr * 64 + fm * 16 + (lane >> 4) * 4;
        float4 bl = *(const float4*)&blendE[i0];
        #pragma unroll
        for (int fn = 0; fn < 2; ++fn) {
            int j = on + wc * 32 + fn * 16 + (lane & 15);
            float bs = biasE[j];
            #pragma unroll
            for (int r = 0; r < 4; ++r)
                Ye[(size_t)(i0 + r) * 512 + j] = f2bf((acc[fm][fn][r] + bs) * ((&bl.x)[r]));
        }
    }

    int lb = (blockIdx.z * 8 + blockIdx.y) * 4 + blockIdx.x;
    cvt_chunk(csrc, cdst, lb * 1024 + threadIdx.x);
    cvt_chunk(csrc, cdst, lb * 1024 + 512 + threadIdx.x);
}

// ======== layers 1/2: bf16, K=512 fixed, depth-4 gload16, 1 barrier/iter ========
__global__ __launch_bounds__(512) void k_gemm(
    const unsigned short* __restrict__ A,
    const unsigned short* __restrict__ W,
    const float* __restrict__ blend, const float* __restrict__ bias,
    unsigned short* __restrict__ Y,
    int N, int ldy,
    const float* __restrict__ csrc, unsigned short* __restrict__ cdst, int nchunk)
{
    __shared__ unsigned short As[4][4096];   // 32 KB
    __shared__ unsigned short Bs[4][4096];   // 32 KB

    const int e  = blockIdx.z;
    const int bm = blockIdx.y * 128;
    const int on = blockIdx.x * 128;
    const int t  = threadIdx.x, lane = t & 63, w = t >> 6;
    const int wr = w >> 2, wc = w & 3;

    const unsigned short* Wt = W + (size_t)e * N * 512;
    // pre-swizzled source lane (rule #21): linear gload dest + permuted global src
    const int l2 = lane ^ ((lane >> 3) & 7);
    const int sr = l2 >> 2, sce = (l2 & 3) * 8;
    const int ra = w * 16 + sr;
    int rb = on + ra; if (rb > N - 1) rb = N - 1;
    const unsigned short* gA = A  + (size_t)(bm + ra) * 512 + sce;
    const unsigned short* gB = Wt + (size_t)rb * 512 + sce;

#define STAGE(buf, kt) do { int _k0 = (kt) * 32;                       \
        gload16(gA + _k0, &As[(buf)][w * 512]);                        \
        gload16(gB + _k0, &Bs[(buf)][w * 512]); } while (0)

#define COMPUTE(cur) do {                                                          \
        short8 af[4], bfr[2];                                                      \
        _Pragma("unroll")                                                          \
        for (int fm = 0; fm < 4; ++fm)                                             \
            af[fm] = lds_read_swz(As[(cur)], wr * 64 + fm * 16 + (lane & 15), (lane >> 4) * 16); \
        _Pragma("unroll")                                                          \
        for (int fn = 0; fn < 2; ++fn)                                             \
            bfr[fn] = lds_read_swz(Bs[(cur)], wc * 32 + fn * 16 + (lane & 15), (lane >> 4) * 16); \
        _Pragma("unroll")                                                          \
        for (int fm = 0; fm < 4; ++fm)                                             \
            _Pragma("unroll")                                                      \
            for (int fn = 0; fn < 2; ++fn)                                         \
                acc[fm][fn] = __builtin_amdgcn_mfma_f32_16x16x32_bf16(             \
                    af[fm], bfr[fn], acc[fm][fn], 0, 0, 0);                        \
    } while (0)

    f32x4 acc[4][2] = {};
    STAGE(0, 0); STAGE(1, 1); STAGE(2, 2);   // 6 loads in flight / thread

    // iters 0..12: steady state — wait own tile-kt loads (leave 4 newest), stage kt+3
    for (int kt = 0; kt < 13; ++kt) {
        WAITV(4);
        BAR();                                // tile kt in LDS; tile kt-1 reads done
        STAGE((kt + 3) & 3, kt + 3);          // overwrite tile kt-1's buffer
        COMPUTE(kt & 3);
    }
    // kt=13,14,15 peeled (no more staging)
    WAITV(4); BAR(); COMPUTE(1);
    WAITV(2); BAR(); COMPUTE(2);
    WAITV(0); BAR(); COMPUTE(3);
#undef STAGE

    const float* blendE = blend + e * 1024;
    const float* biasE  = bias + (size_t)e * N;
    unsigned short* Ye  = Y + (size_t)e * 1024 * ldy;
    #pragma unroll
    for (int fm = 0; fm < 4; ++fm) {
        int i0 = bm + wr * 64 + fm * 16 + (lane >> 4) * 4;
        float4 bl = *(const float4*)&blendE[i0];
        #pragma unroll
        for (int fn = 0; fn < 2; ++fn) {
            int j = on + wc * 32 + fn * 16 + (lane & 15);
            if (j < N) {
                float bs = biasE[j];
                #pragma unroll
                for (int r = 0; r < 4; ++r)
                    Ye[(size_t)(i0 + r) * ldy + j] = f2bf((acc[fm][fn][r] + bs) * ((&bl.x)[r]));
            }
        }
    }

    if (cdst) {
        int lb = (blockIdx.z * 8 + blockIdx.y) * gridDim.x + blockIdx.x;
        #pragma unroll
        for (int q = 0; q < 2; ++q) {
            int tl = q * 512 + threadIdx.x;
            if (tl < nchunk) cvt_chunk(csrc, cdst, lb * nchunk + tl);
        }
    }
}

// ---- sum 8 bf16 planes + ELU -> bf16 (N=512), 8 elems/thread ----
__global__ __launch_bounds__(256) void k_reduce8(
    const unsigned short* __restrict__ Y, unsigned short* __restrict__ out)
{
    int idx = blockIdx.x * 256 + threadIdx.x;
    int b  = idx >> 6;
    int o0 = (idx & 63) * 8;
    size_t base = (size_t)b * 512 + o0;
    float s[8] = {};
    #pragma unroll
    for (int p = 0; p < 8; ++p) {
        int4 v = *(const int4*)&Y[base + (size_t)p * 1024 * 512];
        const unsigned short* u = (const unsigned short*)&v;
        #pragma unroll
        for (int r = 0; r < 8; ++r) s[r] += bf2f(u[r]);
    }
    union { unsigned short u[8]; int4 v; } rr;
    #pragma unroll
    for (int r = 0; r < 8; ++r) {
        float v = (s[r] > 0.f) ? s[r] : expm1f(s[r]);
        rr.u[r] = f2bf(v);
    }
    *(int4*)&out[base] = rr.v;
}

// ---- final: sum 8 planes (ldy=320), fp32 out, N=311 ----
__global__ __launch_bounds__(256) void k_reduce_last(
    const unsigned short* __restrict__ Y, float* __restrict__ out)
{
    int idx = blockIdx.x * 256 + threadIdx.x;
    if (idx >= 1024 * 40) return;
    int b  = idx / 40;
    int o0 = (idx - b * 40) * 8;
    size_t base = (size_t)b * 320 + o0;
    float s[8] = {};
    #pragma unroll
    for (int p = 0; p < 8; ++p) {
        int4 v = *(const int4*)&Y[base + (size_t)p * 1024 * 320];
        const unsigned short* u = (const unsigned short*)&v;
        #pragma unroll
        for (int r = 0; r < 8; ++r) s[r] += bf2f(u[r]);
    }
    #pragma unroll
    for (int r = 0; r < 8; ++r)
        if (o0 + r < 311) out[(size_t)b * 311 + o0 + r] = s[r];
}

extern "C" void kernel_launch(void* const* d_in, const int* in_sizes, int n_in,
                              void* d_out, int out_size, void* d_ws, size_t ws_size,
                              hipStream_t stream) {
    const float* x     = (const float*)d_in[0];
    const float* blend = (const float*)d_in[1];
    const float* w0    = (const float*)d_in[2];
    const float* b0    = (const float*)d_in[3];
    const float* w1    = (const float*)d_in[4];
    const float* b1    = (const float*)d_in[5];
    const float* w2    = (const float*)d_in[6];
    const float* b2    = (const float*)d_in[7];

    char* ws = (char*)d_ws;
    unsigned short* w1b = (unsigned short*)(ws + 0);         // 4,194,304
    unsigned short* w2b = (unsigned short*)(ws + 4194304);   // 2,547,712
    unsigned short* h1b = (unsigned short*)(ws + 6742016);   // 1,048,576
    unsigned short* h2b = (unsigned short*)(ws + 7790592);   // 1,048,576
    unsigned short* yb  = (unsigned short*)(ws + 8839168);   // 8,388,608 (8 bf16 planes)

    // layer 0: fp32-direct GEMM + tail-convert w1
    k_gemm0<<<dim3(4, 8, 8), 512, 0, stream>>>(x, w0, blend, b0, yb, w1, w1b);
    k_reduce8<<<256, 256, 0, stream>>>(yb, h1b);

    // layer 1: bf16 GEMM + tail-convert w2
    k_gemm<<<dim3(4, 8, 8), 512, 0, stream>>>(h1b, w1b, blend, b1, yb, 512, 512,
                                              w2, w2b, 622);
    k_reduce8<<<256, 256, 0, stream>>>(yb, h2b);

    // layer 2: bf16 GEMM, N=311 (ldy=320)
    k_gemm<<<dim3(3, 8, 8), 512, 0, stream>>>(h2b, w2b, blend, b2, yb, 311, 320,
                                              nullptr, nullptr, 0);
    k_reduce_last<<<160, 256, 0, stream>>>(yb, (float*)d_out);
}